// Round 7
// baseline (522.562 us; speedup 1.0000x reference)
//
#include <hip/hip_runtime.h>
#include <cstddef>
#include <cstdint>

#define N_NODES 50000
#define D_NODES 20000
#define M_NODES 30000
#define E_EDGES 800000
#define PAIRS_N 100000

typedef unsigned short u16;
typedef unsigned int u32;
typedef short bf16x8 __attribute__((ext_vector_type(8)));
typedef float f32x4 __attribute__((ext_vector_type(4)));

__device__ __forceinline__ float bf2f(u16 u) {
  u32 v = ((u32)u) << 16;
  return __builtin_bit_cast(float, v);
}
__device__ __forceinline__ u16 f2bf(float f) {
  u32 u = __builtin_bit_cast(u32, f);
  u32 r = (u + 0x7fffu + ((u >> 16) & 1u)) >> 16;  // RNE
  return (u16)r;
}
__device__ __forceinline__ u32 pk2(float x, float y) {
  return (u32)f2bf(x) | ((u32)f2bf(y) << 16);
}
__device__ __forceinline__ bf16x8 pk8(float4 a, float4 b) {
  uint4 q = make_uint4(pk2(a.x, a.y), pk2(a.z, a.w), pk2(b.x, b.y), pk2(b.z, b.w));
  return __builtin_bit_cast(bf16x8, q);
}

// ---------------- weight conversion (5 mats -> bf16, one launch) ----------------
__global__ void wconv_kernel(const float* s0, const float* s1, const float* s2,
                             const float* s3, const float* s4,
                             u16* d0, u16* d1, u16* d2, u16* d3, u16* d4) {
  int i = blockIdx.x * 256 + threadIdx.x;  // quad index
  const float* s; u16* d; int l;
  if      (i < 16384) { s = s0; d = d0; l = i; }
  else if (i < 32768) { s = s1; d = d1; l = i - 16384; }
  else if (i < 53248) { s = s2; d = d2; l = i - 32768; }
  else if (i < 73728) { s = s3; d = d3; l = i - 53248; }
  else if (i < 81920) { s = s4; d = d4; l = i - 73728; }
  else return;
  float4 v = *(const float4*)(s + (size_t)l * 4);
  ushort4 o;
  o.x = f2bf(v.x); o.y = f2bf(v.y); o.z = f2bf(v.z); o.w = f2bf(v.w);
  *(ushort4*)(d + (size_t)l * 4) = o;
}

// ---------------- weight combine: G_k = sum_{p+j=k} fc_p * W'_pj * W_j ----------
__global__ void wcomb1_kernel(const float* __restrict__ l1w, const float* __restrict__ l0w,
                              float* __restrict__ Tmp) {
  int pj = blockIdx.x;          // 0..8
  int p = pj / 3, j = pj % 3;
  int o = blockIdx.y;           // 0..127
  int i = threadIdx.x;          // 0..127
  const float* wp = l1w + (size_t)p * 49152 + (size_t)o * 384 + 128 * j;
  const float* wj = l0w + (size_t)j * 16384 + i;
  float acc = 0.f;
#pragma unroll 4
  for (int t = 0; t < 128; ++t) acc += wp[t] * wj[(size_t)t * 128];
  Tmp[(size_t)pj * 16384 + (size_t)o * 128 + i] = acc;
}
__global__ void wcomb2_kernel(const float* __restrict__ fcw, const float* __restrict__ Tmp,
                              u16* __restrict__ G) {
  int k = blockIdx.x;           // 0..4
  int of = blockIdx.y;          // 0..127
  int i = threadIdx.x;          // 0..127
  float acc = 0.f;
  int plo = (k > 2) ? (k - 2) : 0;
  int phi = (k < 2) ? k : 2;
  for (int p = plo; p <= phi; ++p) {
    int j = k - p;
    const float* fp = fcw + (size_t)of * 384 + 128 * p;
    const float* tp = Tmp + (size_t)(p * 3 + j) * 16384 + i;
#pragma unroll 4
    for (int t = 0; t < 128; ++t) acc += fp[t] * tp[(size_t)t * 128];
  }
  G[(size_t)of * 640 + 128 * k + i] = f2bf(acc);
}

// ---------------- CSR build ----------------
__global__ void zero_int_kernel(int* p, int n) {
  int i = blockIdx.x * 256 + threadIdx.x;
  if (i < n) p[i] = 0;
}
__global__ void deg_count_kernel(const int* __restrict__ dst, int* __restrict__ degs, int e) {
  int i = blockIdx.x * 256 + threadIdx.x;
  if (i < e) atomicAdd(&degs[dst[i]], 1);
}
__global__ void norm_reduce_kernel(const int* __restrict__ degs, float* __restrict__ norm,
                                   int n, int* __restrict__ bsums) {
  __shared__ int s[256];
  int t = threadIdx.x;
  int i = blockIdx.x * 256 + t;
  int d = (i < n) ? degs[i] : 0;
  if (i < n) norm[i] = rsqrtf(fmaxf((float)d, 1.0f));
  s[t] = d;
  __syncthreads();
  for (int st = 128; st > 0; st >>= 1) {
    if (t < st) s[t] += s[t + st];
    __syncthreads();
  }
  if (t == 0) bsums[blockIdx.x] = s[0];
}
__global__ void scan_small_kernel(int* b, int nb) {
  __shared__ int s[256];
  int t = threadIdx.x;
  int orig = (t < nb) ? b[t] : 0;
  s[t] = orig;
  __syncthreads();
  for (int st = 1; st < 256; st <<= 1) {
    int v = (t >= st) ? s[t - st] : 0;
    __syncthreads();
    s[t] += v;
    __syncthreads();
  }
  if (t < nb) b[t] = s[t] - orig;
}
__global__ void scan_final_kernel(const int* __restrict__ degs, const int* __restrict__ boff,
                                  int* __restrict__ out, int* __restrict__ cursor,
                                  int n, int total) {
  __shared__ int s[256];
  int t = threadIdx.x;
  int i = blockIdx.x * 256 + t;
  int orig = (i < n) ? degs[i] : 0;
  s[t] = orig;
  __syncthreads();
  for (int st = 1; st < 256; st <<= 1) {
    int v = (t >= st) ? s[t - st] : 0;
    __syncthreads();
    s[t] += v;
    __syncthreads();
  }
  if (i < n) {
    int v = boff[blockIdx.x] + s[t] - orig;
    out[i] = v;
    cursor[i] = v;
  }
  if (i == 0) out[n] = total;
}
__global__ void fill_csr_kernel(const int* __restrict__ esrc, const int* __restrict__ edst,
                                int* __restrict__ cursor, int* __restrict__ csr_src, int e) {
  int i = blockIdx.x * 256 + threadIdx.x;
  if (i < e) {
    int p = atomicAdd(&cursor[edst[i]], 1);
    csr_src[p] = esrc[i];
  }
}

// ---------------- wave-per-node 128-wide propagation on pre-scaled input --------
__global__ void prop_kernel(const u16* __restrict__ in,
                            u16* __restrict__ outu, int ldu, int cOff,
                            u16* __restrict__ outs,
                            const int* __restrict__ off, const int* __restrict__ srcs,
                            const float* __restrict__ norm, int nnodes) {
  const int node = blockIdx.x * 4 + (threadIdx.x >> 6);
  if (node >= nnodes) return;
  const int lane = threadIdx.x & 63;
  const int e0 = off[node], e1 = off[node + 1];
  float a0 = 0.f, a1 = 0.f;
  const u16* basec = in + (lane << 1);
  for (int base = e0; base < e1; base += 64) {
    int nE = e1 - base; if (nE > 64) nE = 64;
    int myE = srcs[base + ((lane < nE) ? lane : (nE - 1))];
    int i = 0;
    for (; i + 8 <= nE; i += 8) {
      int s0 = __builtin_amdgcn_readlane(myE, i + 0);
      int s1 = __builtin_amdgcn_readlane(myE, i + 1);
      int s2 = __builtin_amdgcn_readlane(myE, i + 2);
      int s3 = __builtin_amdgcn_readlane(myE, i + 3);
      int s4 = __builtin_amdgcn_readlane(myE, i + 4);
      int s5 = __builtin_amdgcn_readlane(myE, i + 5);
      int s6 = __builtin_amdgcn_readlane(myE, i + 6);
      int s7 = __builtin_amdgcn_readlane(myE, i + 7);
      u32 v0 = *(const u32*)(basec + ((size_t)s0 << 7));
      u32 v1 = *(const u32*)(basec + ((size_t)s1 << 7));
      u32 v2 = *(const u32*)(basec + ((size_t)s2 << 7));
      u32 v3 = *(const u32*)(basec + ((size_t)s3 << 7));
      u32 v4 = *(const u32*)(basec + ((size_t)s4 << 7));
      u32 v5 = *(const u32*)(basec + ((size_t)s5 << 7));
      u32 v6 = *(const u32*)(basec + ((size_t)s6 << 7));
      u32 v7 = *(const u32*)(basec + ((size_t)s7 << 7));
      a0 += bf2f((u16)v0); a1 += bf2f((u16)(v0 >> 16));
      a0 += bf2f((u16)v1); a1 += bf2f((u16)(v1 >> 16));
      a0 += bf2f((u16)v2); a1 += bf2f((u16)(v2 >> 16));
      a0 += bf2f((u16)v3); a1 += bf2f((u16)(v3 >> 16));
      a0 += bf2f((u16)v4); a1 += bf2f((u16)(v4 >> 16));
      a0 += bf2f((u16)v5); a1 += bf2f((u16)(v5 >> 16));
      a0 += bf2f((u16)v6); a1 += bf2f((u16)(v6 >> 16));
      a0 += bf2f((u16)v7); a1 += bf2f((u16)(v7 >> 16));
    }
    for (; i < nE; ++i) {
      int s = __builtin_amdgcn_readlane(myE, i);
      u32 v = *(const u32*)(basec + ((size_t)s << 7));
      a0 += bf2f((u16)v); a1 += bf2f((u16)(v >> 16));
    }
  }
  float nd = norm[node];
  *(u32*)(outu + (size_t)node * ldu + cOff + (lane << 1)) = pk2(a0 * nd, a1 * nd);
  if (outs) {
    float nd2 = nd * nd;
    *(u32*)(outs + ((size_t)node << 7) + (lane << 1)) = pk2(a0 * nd2, a1 * nd2);
  }
}

// ---------------- LDS-free direct-fragment MFMA GEMM ----------------
// Block = 256 thr = 4 waves; wave (rg=w>>1, ch=w&1) computes rows [brow+rg*32, +32)
// x cols [ch*64, +64). Fragments loaded straight from global (A rows, W rows).
// Segmented rows (blocks >= splitB use b-side A/W/bias, rows from rowD).
// fp32 A segments converted inline. Gather via gsrc/gdst (k<K1 -> gsrc row).
// act: 0 none, 1 ELU, 3 fused p0+score (Cu unused).
__global__ __launch_bounds__(256) void mfma_gemm_kernel(
    const void* __restrict__ A1a, const void* __restrict__ A1b, int lda1, int K1, int a1f32,
    const void* __restrict__ A2a, const void* __restrict__ A2b, int lda2, int K2, int a2f32,
    const int* __restrict__ gsrc, const int* __restrict__ gdst,
    const u16* __restrict__ Wa, const u16* __restrict__ Wb,
    const float* __restrict__ biasa, const float* __restrict__ biasb,
    int splitB, int rowD, int boundA, int nrows,
    u16* __restrict__ Cu, int ldcu, int colOff,
    u16* __restrict__ Cs, const float* __restrict__ normp,
    const float* __restrict__ p1w, const float* __restrict__ p1b, float* __restrict__ outf,
    int act) {
  __shared__ float sred[2][64];
  const int tid = threadIdx.x;
  const int w = tid >> 6, lane = tid & 63;
  const int ch = w & 1, rg = w >> 1;
  const int fr = lane & 15, fg = lane >> 4;
  const bool segb = (int)blockIdx.x >= splitB;
  const int brow = segb ? rowD + ((int)blockIdx.x - splitB) * 64 : (int)blockIdx.x * 64;
  const int bound = segb ? nrows : boundA;
  const void* A1 = segb ? A1b : A1a;
  const void* A2 = segb ? A2b : A2a;
  const u16* W = segb ? Wb : Wa;
  const float* bias = segb ? biasb : biasa;
  const int K = K1 + K2;

  // fragment rows (clamped) + gather indices, hoisted
  int r0 = brow + rg * 32 + fr;
  int r1 = r0 + 16;
  int c0 = (r0 < bound) ? r0 : (bound - 1);
  int c1 = (r1 < bound) ? r1 : (bound - 1);
  int gA0, gA1, gB0, gB1;
  if (gsrc) { gA0 = gsrc[c0]; gA1 = gsrc[c1]; gB0 = gdst[c0]; gB1 = gdst[c1]; }
  else { gA0 = c0; gA1 = c1; gB0 = c0; gB1 = c1; }

  const u16* wbase = W + (size_t)(ch * 64 + fr) * K + fg * 8;  // + n*16*K + kc (+32)

  f32x4 acc[2][4];
#pragma unroll
  for (int m = 0; m < 2; ++m)
#pragma unroll
    for (int n = 0; n < 4; ++n) acc[m][n] = (f32x4){0.f, 0.f, 0.f, 0.f};

  for (int kc = 0; kc < K; kc += 64) {
    const bool seg1 = kc < K1;
    const int kk = (seg1 ? kc : kc - K1) + fg * 8;
    const int ld = seg1 ? lda1 : lda2;
    const int isf = seg1 ? a1f32 : a2f32;
    const void* Av = seg1 ? A1 : A2;
    const int ra = seg1 ? gA0 : gB0;
    const int rb = seg1 ? gA1 : gB1;

    // ---- A fragments (2 rows x 2 k-halves)
    bf16x8 aAh0, aAh1, aBh0, aBh1;
    if (isf) {
      const float* pa = (const float*)Av + (size_t)ra * ld + kk;
      const float* pb = (const float*)Av + (size_t)rb * ld + kk;
      float4 a00 = ((const float4*)pa)[0], a01 = ((const float4*)pa)[1];
      float4 a10 = ((const float4*)(pa + 32))[0], a11 = ((const float4*)(pa + 32))[1];
      float4 b00 = ((const float4*)pb)[0], b01 = ((const float4*)pb)[1];
      float4 b10 = ((const float4*)(pb + 32))[0], b11 = ((const float4*)(pb + 32))[1];
      aAh0 = pk8(a00, a01); aAh1 = pk8(a10, a11);
      aBh0 = pk8(b00, b01); aBh1 = pk8(b10, b11);
    } else {
      const u16* pa = (const u16*)Av + (size_t)ra * ld + kk;
      const u16* pb = (const u16*)Av + (size_t)rb * ld + kk;
      aAh0 = *(const bf16x8*)pa; aAh1 = *(const bf16x8*)(pa + 32);
      aBh0 = *(const bf16x8*)pb; aBh1 = *(const bf16x8*)(pb + 32);
    }
    // ---- W fragments (4 col-frags x 2 k-halves)
    bf16x8 bh0[4], bh1[4];
#pragma unroll
    for (int n = 0; n < 4; ++n) {
      const u16* wp = wbase + (size_t)n * 16 * K + kc;
      bh0[n] = *(const bf16x8*)wp;
      bh1[n] = *(const bf16x8*)(wp + 32);
    }
    // ---- 16 MFMA
#pragma unroll
    for (int n = 0; n < 4; ++n) {
      acc[0][n] = __builtin_amdgcn_mfma_f32_16x16x32_bf16(aAh0, bh0[n], acc[0][n], 0, 0, 0);
      acc[1][n] = __builtin_amdgcn_mfma_f32_16x16x32_bf16(aBh0, bh0[n], acc[1][n], 0, 0, 0);
    }
#pragma unroll
    for (int n = 0; n < 4; ++n) {
      acc[0][n] = __builtin_amdgcn_mfma_f32_16x16x32_bf16(aAh1, bh1[n], acc[0][n], 0, 0, 0);
      acc[1][n] = __builtin_amdgcn_mfma_f32_16x16x32_bf16(aBh1, bh1[n], acc[1][n], 0, 0, 0);
    }
  }

  if (act == 3) {
    // fused p0 bias+ReLU, dot with p1w, sigmoid -> outf[row]
    float part[2][4];
#pragma unroll
    for (int m = 0; m < 2; ++m)
#pragma unroll
      for (int i = 0; i < 4; ++i) part[m][i] = 0.f;
#pragma unroll
    for (int n = 0; n < 4; ++n) {
      int ccol = ch * 64 + n * 16 + fr;
      float b = bias[ccol];
      float pw = p1w[ccol];
#pragma unroll
      for (int m = 0; m < 2; ++m)
#pragma unroll
        for (int i = 0; i < 4; ++i) {
          float v = fmaxf(acc[m][n][i] + b, 0.f);
          part[m][i] += v * pw;
        }
    }
#pragma unroll
    for (int mask = 1; mask <= 8; mask <<= 1)
#pragma unroll
      for (int m = 0; m < 2; ++m)
#pragma unroll
        for (int i = 0; i < 4; ++i) part[m][i] += __shfl_xor(part[m][i], mask);
    if (fr == 0) {
#pragma unroll
      for (int m = 0; m < 2; ++m)
#pragma unroll
        for (int i = 0; i < 4; ++i) sred[ch][rg * 32 + m * 16 + fg * 4 + i] = part[m][i];
    }
    __syncthreads();
    if (tid < 64) {
      int row = brow + tid;
      if (row < bound) {
        float s = sred[0][tid] + sred[1][tid] + p1b[0];
        outf[row] = 1.f / (1.f + expf(-s));
      }
    }
    return;
  }

  // ---- epilogue: D lane map col=lane&15, row=(lane>>4)*4+i  [m89]
#pragma unroll
  for (int m = 0; m < 2; ++m) {
#pragma unroll
    for (int n = 0; n < 4; ++n) {
      int ccol = ch * 64 + n * 16 + fr;
      float b = bias ? bias[ccol] : 0.f;
#pragma unroll
      for (int i = 0; i < 4; ++i) {
        int row = brow + rg * 32 + m * 16 + fg * 4 + i;
        if (row < bound) {
          float v = acc[m][n][i] + b;
          if (act == 1) v = (v > 0.f) ? v : (expf(v) - 1.f);
          Cu[(size_t)row * ldcu + colOff + ccol] = f2bf(v);
          if (Cs) Cs[((size_t)row << 7) + ccol] = f2bf(v * normp[row]);
        }
      }
    }
  }
}

// ---------------- host launcher ----------------
extern "C" void kernel_launch(void* const* d_in, const int* in_sizes, int n_in,
                              void* d_out, int out_size, void* d_ws, size_t ws_size,
                              hipStream_t stream) {
  const float* d_sim   = (const float*)d_in[0];
  const float* m_sim   = (const float*)d_in[1];
  const int*   e_src   = (const int*)d_in[2];
  const int*   e_dst   = (const int*)d_in[3];
  const int*   p_src   = (const int*)d_in[4];
  const int*   p_dst   = (const int*)d_in[5];
  const float* d_fc_w  = (const float*)d_in[6];
  const float* d_fc_b  = (const float*)d_in[7];
  const float* m_fc_w  = (const float*)d_in[8];
  const float* m_fc_b  = (const float*)d_in[9];
  const float* l0_w    = (const float*)d_in[10];
  const float* l1_w    = (const float*)d_in[11];
  const float* fc_w    = (const float*)d_in[12];
  const float* d_fc1_w = (const float*)d_in[13];
  const float* d_fc1_b = (const float*)d_in[14];
  const float* m_fc1_w = (const float*)d_in[15];
  const float* m_fc1_b = (const float*)d_in[16];
  const float* p0_w    = (const float*)d_in[17];
  const float* p0_b    = (const float*)d_in[18];
  const float* p1_w    = (const float*)d_in[19];
  const float* p1_b    = (const float*)d_in[20];
  float* out = (float*)d_out;

  const int N = N_NODES, D = D_NODES, M = M_NODES, E = E_EDGES, NP = PAIRS_N;

  // ---- workspace layout (u16 units)
  u16* ws16 = (u16*)d_ws;
  u16* HCAT = ws16;                         // [N,640]
  u16* HSa  = HCAT + (size_t)N * 640;       // [N,128]
  u16* HSb  = HSa + (size_t)N * 128;        // [N,128]
  u16* FE   = HSb + (size_t)N * 128;        // [N,128] feats
  u16* HB   = FE  + (size_t)N * 128;        // [N,128] h
  u16* wb_dfc  = HB + (size_t)N * 128;      // 65536
  u16* wb_mfc  = wb_dfc  + 65536;
  u16* wb_dfc1 = wb_mfc  + 65536;           // 81920
  u16* wb_mfc1 = wb_dfc1 + 81920;
  u16* wb_p0   = wb_mfc1 + 81920;           // 32768
  u16* wb_G    = wb_p0   + 32768;           // 81920 ([128][640])
  u16* wend    = wb_G    + 81920;
  size_t off16 = (size_t)(wend - ws16);
  off16 = (off16 + 1) & ~(size_t)1;
  float* Tmp   = (float*)(ws16 + off16);    // 9*128*128 f32
  float* normp = Tmp + 9 * 16384;
  int* degs    = (int*)(normp + N);
  int* csr_off = degs + N;                  // N+1
  int* cursor  = csr_off + N + 1;           // N
  int* csr_src = cursor + N;                // E
  int* bsums   = csr_src + E;               // <=256

  const int nb = (N + 255) / 256;
  const int eb = (E + 255) / 256;

  // ---- conversions + weight combine (independent of graph/CSR)
  wconv_kernel<<<320, 256, 0, stream>>>(d_fc_w, m_fc_w, d_fc1_w, m_fc1_w, p0_w,
                                        wb_dfc, wb_mfc, wb_dfc1, wb_mfc1, wb_p0);
  wcomb1_kernel<<<dim3(9, 128), 128, 0, stream>>>(l1_w, l0_w, Tmp);
  wcomb2_kernel<<<dim3(5, 128), 128, 0, stream>>>(fc_w, Tmp, wb_G);

  // ---- degrees, norm, CSR-by-dst
  zero_int_kernel<<<nb, 256, 0, stream>>>(degs, N);
  deg_count_kernel<<<eb, 256, 0, stream>>>(e_dst, degs, E);
  norm_reduce_kernel<<<nb, 256, 0, stream>>>(degs, normp, N, bsums);
  scan_small_kernel<<<1, 256, 0, stream>>>(bsums, nb);
  scan_final_kernel<<<nb, 256, 0, stream>>>(degs, bsums, csr_off, cursor, N, E);
  fill_csr_kernel<<<eb, 256, 0, stream>>>(e_src, e_dst, cursor, csr_src, E);

  const int GDseg = (D + 63) / 64;           // 313
  const int GMseg = (M + 63) / 64;           // 469
  const int GSEG = GDseg + GMseg;            // 782
  const int GN = (N + 63) / 64;              // 782
  const int GP = (NP + 63) / 64;             // 1563
  const int GPROP = (N + 3) / 4;             // 12500

  // ---- proj (fp32 sims direct, segmented): H0 -> HCAT[:,0:128], scaled H0 -> HSa
  mfma_gemm_kernel<<<GSEG, 256, 0, stream>>>(
      d_sim, m_sim, 512, 512, 1, nullptr, nullptr, 0, 0, 0, nullptr, nullptr,
      wb_dfc, wb_mfc, d_fc_b, m_fc_b, GDseg, D, D, N,
      HCAT, 640, 0, HSa, normp, nullptr, nullptr, nullptr, 0);

  // ---- 4 sequential 128-wide props: H1..H4 -> HCAT col-blocks, scaled ping-pong
  prop_kernel<<<GPROP, 256, 0, stream>>>(HSa, HCAT, 640, 128, HSb, csr_off, csr_src, normp, N);
  prop_kernel<<<GPROP, 256, 0, stream>>>(HSb, HCAT, 640, 256, HSa, csr_off, csr_src, normp, N);
  prop_kernel<<<GPROP, 256, 0, stream>>>(HSa, HCAT, 640, 384, HSb, csr_off, csr_src, normp, N);
  prop_kernel<<<GPROP, 256, 0, stream>>>(HSb, HCAT, 640, 512, nullptr, csr_off, csr_src, normp, N);

  // ---- collapsed mixhop+fc: feats = HCAT [N,640] @ G^T -> FE
  mfma_gemm_kernel<<<GN, 256, 0, stream>>>(
      HCAT, HCAT, 640, 640, 0, nullptr, nullptr, 0, 0, 0, nullptr, nullptr,
      wb_G, wb_G, nullptr, nullptr, GN, 0, N, N,
      FE, 128, 0, nullptr, normp, nullptr, nullptr, nullptr, 0);

  // ---- fc1 (+ELU): [FE bf16 | sims fp32] -> h in HB
  mfma_gemm_kernel<<<GSEG, 256, 0, stream>>>(
      FE, FE, 128, 128, 0, d_sim, m_sim, 512, 512, 1, nullptr, nullptr,
      wb_dfc1, wb_mfc1, d_fc1_b, m_fc1_b, GDseg, D, D, N,
      HB, 128, 0, nullptr, normp, nullptr, nullptr, nullptr, 1);

  // ---- predictor p0 (gathered concat) + ReLU + dot(p1) + sigmoid -> out
  mfma_gemm_kernel<<<GP, 256, 0, stream>>>(
      HB, HB, 128, 128, 0, HB, HB, 128, 128, 0, p_src, p_dst,
      wb_p0, wb_p0, p0_b, p0_b, GP, 0, NP, NP,
      nullptr, 128, 0, nullptr, normp, p1_w, p1_b, out, 3);

  (void)in_sizes; (void)n_in; (void)out_size; (void)ws_size;
}